// Round 1
// baseline (505.557 us; speedup 1.0000x reference)
//
#include <hip/hip_runtime.h>

// OU process sampling: solve upper-bidiagonal U x = z along last axis.
// x[i] = a[i]*x[i+1] + b[i],  a[i] = -sup[i+1]/diag[i] (a[L-1]=0), b[i] = z[i]/diag[i]
// Chunked parallel scan: 1 block per row, 32 elems/thread, block-wide affine
// suffix scan over the 256 chunk maps, then exact fix-up sweep.

#define LN  8192   // L
#define TPB 256    // threads per block
#define K   32     // LN / TPB, elements per thread

__global__ void ou_prep(const float* __restrict__ diag,
                        const float* __restrict__ sup,
                        float* __restrict__ a,
                        float* __restrict__ binv) {
    int i = blockIdx.x * blockDim.x + threadIdx.x;
    if (i < LN) {
        float inv = 1.0f / diag[i];
        binv[i] = inv;
        float e = (i + 1 < LN) ? sup[i + 1] : 0.0f;  // e[L-1] = 0
        a[i] = -e * inv;
    }
}

__global__ __launch_bounds__(TPB) void ou_solve(
    const float* __restrict__ z,
    const float* __restrict__ a,
    const float* __restrict__ binv,
    float* __restrict__ out) {
    __shared__ float sA[TPB];
    __shared__ float sB[TPB];
    const int t = threadIdx.x;
    const long long base = (long long)blockIdx.x * LN + (long long)t * K;
    const int cbase = t * K;

    float av[K], bv[K];
    const float4* z4 = reinterpret_cast<const float4*>(z + base);
    const float4* a4 = reinterpret_cast<const float4*>(a + cbase);
    const float4* i4 = reinterpret_cast<const float4*>(binv + cbase);
#pragma unroll
    for (int j = 0; j < K / 4; ++j) {
        float4 zz = z4[j];
        float4 aa = a4[j];
        float4 ii = i4[j];
        av[4 * j + 0] = aa.x; av[4 * j + 1] = aa.y;
        av[4 * j + 2] = aa.z; av[4 * j + 3] = aa.w;
        bv[4 * j + 0] = zz.x * ii.x; bv[4 * j + 1] = zz.y * ii.y;
        bv[4 * j + 2] = zz.z * ii.z; bv[4 * j + 3] = zz.w * ii.w;
    }

    // Pass 1: zero-boundary solve of this chunk -> (C = prod a, Y = head value)
    float x = 0.0f, p = 1.0f;
#pragma unroll
    for (int j = K - 1; j >= 0; --j) {
        x = fmaf(av[j], x, bv[j]);
        p *= av[j];
    }
    sA[t] = p;
    sB[t] = x;
    __syncthreads();

    // Hillis-Steele suffix scan of affine maps: g_t = f_t ∘ f_{t+1} ∘ ... ∘ f_255
    // (A,B)∘(A2,B2) = (A*A2, B + A*B2); identity = (1,0).
    for (int off = 1; off < TPB; off <<= 1) {
        float A = sA[t], Bv = sB[t];
        float A2 = 1.0f, B2 = 0.0f;
        if (t + off < TPB) { A2 = sA[t + off]; B2 = sB[t + off]; }
        float nA = A * A2;
        float nB = fmaf(A, B2, Bv);
        __syncthreads();
        sA[t] = nA;
        sB[t] = nB;
        __syncthreads();
    }
    // True boundary value entering this chunk from the right: X[t+1] = sB[t+1]
    float xcur = (t + 1 < TPB) ? sB[t + 1] : 0.0f;

    // Pass 2: exact sweep with the correct boundary; reuse bv[] as result store.
#pragma unroll
    for (int j = K - 1; j >= 0; --j) {
        xcur = fmaf(av[j], xcur, bv[j]);
        bv[j] = xcur;
    }

    float4* o4 = reinterpret_cast<float4*>(out + base);
#pragma unroll
    for (int j = 0; j < K / 4; ++j) {
        o4[j] = make_float4(bv[4 * j + 0], bv[4 * j + 1],
                            bv[4 * j + 2], bv[4 * j + 3]);
    }
}

extern "C" void kernel_launch(void* const* d_in, const int* in_sizes, int n_in,
                              void* d_out, int out_size, void* d_ws, size_t ws_size,
                              hipStream_t stream) {
    const float* z    = (const float*)d_in[0];   // (B, C, L) fp32
    const float* diag = (const float*)d_in[1];   // (L,)
    const float* sup  = (const float*)d_in[2];   // (L,)
    float* out = (float*)d_out;

    float* a    = (float*)d_ws;        // LN floats
    float* binv = a + LN;              // LN floats (64 KB total scratch)

    const int rows = in_sizes[0] / LN; // B*C = 8192

    ou_prep<<<(LN + TPB - 1) / TPB, TPB, 0, stream>>>(diag, sup, a, binv);
    ou_solve<<<rows, TPB, 0, stream>>>(z, a, binv, out);
}

// Round 2
// 457.268 us; speedup vs baseline: 1.1056x; 1.1056x over previous
//
#include <hip/hip_runtime.h>

// OU process sampling: solve upper-bidiagonal U x = z along last axis.
// x[i] = a[i]*x[i+1] + b[i],  a[i] = -sup[i+1]/diag[i] (a[L-1]=0), b[i] = z[i]/diag[i]
// One block per row. Coalesced global <-> LDS transpose so each wave-level
// global instruction is a dense 1 KiB request (R1 showed the 128B-stride lane
// pattern saturated the VMEM request pipe at ~2 TB/s, not the HBM bytes).
// LDS padded +1 float per 32 -> conflict-free for both staging (coalesced
// order) and chunk (per-thread contiguous) access patterns.

#define LN  8192   // L
#define TPB 256    // threads per block
#define K   32     // LN / TPB, elements per thread
#define PADF(i) ((i) + ((i) >> 5))   // padded LDS float index
#define LDSF (LN + (LN >> 5))        // 8448 floats = 33 KB

__global__ void ou_prep(const float* __restrict__ diag,
                        const float* __restrict__ sup,
                        float* __restrict__ a,
                        float* __restrict__ binv) {
    int i = blockIdx.x * blockDim.x + threadIdx.x;
    if (i < LN) {
        float inv = 1.0f / diag[i];
        binv[i] = inv;
        float e = (i + 1 < LN) ? sup[i + 1] : 0.0f;  // e[L-1] = 0
        a[i] = -e * inv;
    }
}

__global__ __launch_bounds__(TPB) void ou_solve(
    const float* __restrict__ z,
    const float* __restrict__ a,
    const float* __restrict__ binv,
    float* __restrict__ out) {
    __shared__ float lds[LDSF];
    __shared__ float sA[TPB];
    __shared__ float sB[TPB];
    const int t = threadIdx.x;
    const long long rowbase = (long long)blockIdx.x * LN;

    // --- Stage z into LDS, coalesced: thread t iter m covers floats 1024m+4t..+3
    {
        const float4* z4 = reinterpret_cast<const float4*>(z + rowbase);
#pragma unroll
        for (int m = 0; m < 8; ++m) {
            int gi = m * 1024 + 4 * t;
            float4 v = z4[m * 256 + t];
            int li = PADF(gi);  // 4*t%32 + r <= 31: no pad boundary inside the 4
            lds[li + 0] = v.x; lds[li + 1] = v.y;
            lds[li + 2] = v.z; lds[li + 3] = v.w;
        }
    }

    // --- Per-thread chunk coefficients from global (L1/L2-resident, 64 KB total)
    float av[K], bv[K];
    {
        const int cb = t * K;
        const float4* a4 = reinterpret_cast<const float4*>(a + cb);
        const float4* i4 = reinterpret_cast<const float4*>(binv + cb);
        float iv[K];
#pragma unroll
        for (int j = 0; j < K / 4; ++j) {
            float4 aa = a4[j];
            float4 ii = i4[j];
            av[4 * j + 0] = aa.x; av[4 * j + 1] = aa.y;
            av[4 * j + 2] = aa.z; av[4 * j + 3] = aa.w;
            iv[4 * j + 0] = ii.x; iv[4 * j + 1] = ii.y;
            iv[4 * j + 2] = ii.z; iv[4 * j + 3] = ii.w;
        }
        __syncthreads();  // staging complete
        const int lb = 33 * t;  // PADF(32*t + j) = 33*t + j
#pragma unroll
        for (int j = 0; j < K; ++j)
            bv[j] = lds[lb + j] * iv[j];
    }

    // --- Pass 1: zero-boundary chunk solve -> (prod a, head value)
    float x = 0.0f, p = 1.0f;
#pragma unroll
    for (int j = K - 1; j >= 0; --j) {
        x = fmaf(av[j], x, bv[j]);
        p *= av[j];
    }
    sA[t] = p;
    sB[t] = x;
    __syncthreads();

    // --- Hillis-Steele suffix scan of affine maps (A,B)∘(A2,B2)=(A*A2, B+A*B2)
    for (int off = 1; off < TPB; off <<= 1) {
        float A = sA[t], Bv = sB[t];
        float A2 = 1.0f, B2 = 0.0f;
        if (t + off < TPB) { A2 = sA[t + off]; B2 = sB[t + off]; }
        float nA = A * A2;
        float nB = fmaf(A, B2, Bv);
        __syncthreads();
        sA[t] = nA;
        sB[t] = nB;
        __syncthreads();
    }
    float xcur = (t + 1 < TPB) ? sB[t + 1] : 0.0f;

    // --- Pass 2: exact sweep; write results into LDS chunk slots (all chunk
    // reads finished before the scan's first barrier, so overwrite is safe)
    {
        const int lb = 33 * t;
#pragma unroll
        for (int j = K - 1; j >= 0; --j) {
            xcur = fmaf(av[j], xcur, bv[j]);
            lds[lb + j] = xcur;
        }
    }
    __syncthreads();

    // --- Coalesced store from LDS
    {
        float4* o4 = reinterpret_cast<float4*>(out + rowbase);
#pragma unroll
        for (int m = 0; m < 8; ++m) {
            int gi = m * 1024 + 4 * t;
            int li = PADF(gi);
            float4 v = make_float4(lds[li + 0], lds[li + 1],
                                   lds[li + 2], lds[li + 3]);
            o4[m * 256 + t] = v;
        }
    }
}

extern "C" void kernel_launch(void* const* d_in, const int* in_sizes, int n_in,
                              void* d_out, int out_size, void* d_ws, size_t ws_size,
                              hipStream_t stream) {
    const float* z    = (const float*)d_in[0];   // (B, C, L) fp32
    const float* diag = (const float*)d_in[1];   // (L,)
    const float* sup  = (const float*)d_in[2];   // (L,)
    float* out = (float*)d_out;

    float* a    = (float*)d_ws;        // LN floats
    float* binv = a + LN;              // LN floats (64 KB total scratch)

    const int rows = in_sizes[0] / LN; // B*C = 8192

    ou_prep<<<(LN + TPB - 1) / TPB, TPB, 0, stream>>>(diag, sup, a, binv);
    ou_solve<<<rows, TPB, 0, stream>>>(z, a, binv, out);
}